// Round 1
// baseline (1956.760 us; speedup 1.0000x reference)
//
#include <hip/hip_runtime.h>

// ChildSumTreeGRU: BRANCH=4, DEPTH=8, N=87381, X=H=512.
// depth-d nodes contiguous at S[d]=(4^d-1)/3; children of p = 4p+1..4p+4.
// R2: split-bf16 MFMA everywhere; fused leaf gate kernel.
// R3: pre-split ALL GEMM A-operands (x, hsum, rh, child h) to (hi,lo) bf16 at
//     their definition site -> GEMM staging is a pure copy, no per-k-tile
//     split2 VALU. Numerics identical (same split values, computed once).

#define NNODES 87381
#define NINT   21845
#define NLEAF  65536

typedef __attribute__((ext_vector_type(8))) __bf16 bf16x8;
typedef __attribute__((ext_vector_type(4))) float f32x4;

union FU { bf16x8 v; ushort4 u[2]; };

__device__ __forceinline__ float sigmoidf_(float x) { return 1.0f / (1.0f + __expf(-x)); }
__device__ __forceinline__ float tanhf_(float x) { return 2.0f / (1.0f + __expf(-2.0f * x)) - 1.0f; }

__device__ __forceinline__ unsigned short bf_rne(float f) {
  unsigned int u = __float_as_uint(f);
  unsigned int r = u + 0x7FFFu + ((u >> 16) & 1u);
  return (unsigned short)(r >> 16);
}
__device__ __forceinline__ void split2(float f, unsigned short& h, unsigned short& l) {
  h = bf_rne(f);
  l = bf_rne(f - __uint_as_float((unsigned int)h << 16));
}
__device__ __forceinline__ float bf2f(unsigned short h) {
  return __uint_as_float((unsigned int)h << 16);
}

// ---------------- split fp32 -> (hi, lo) bf16 ----------------
__global__ __launch_bounds__(256) void split_k(const float* __restrict__ s,
                                               unsigned short* __restrict__ hi,
                                               unsigned short* __restrict__ lo, int n4) {
  int i = blockIdx.x * 256 + threadIdx.x;
  if (i >= n4) return;
  float4 v = *(const float4*)(s + (size_t)i * 4);
  ushort4 h, l;
  split2(v.x, h.x, l.x); split2(v.y, h.y, l.y);
  split2(v.z, h.z, l.z); split2(v.w, h.w, l.w);
  *(ushort4*)(hi + (size_t)i * 4) = h;
  *(ushort4*)(lo + (size_t)i * 4) = l;
}

// ---------------- MFMA split-bf16 GEMM, A pre-split ----------------
// C[m,n] = epi( sum_k A[m,k]*B[n,k] ), K=512. tile 128x128, BK=32, 4 waves,
// wave = 64x64 = 4x4 tiles of 16x16x32. 3 MFMAs per tile pair (hh, hl, lh).
// EPI 0: plain fp32 store                              (z_e)
// EPI 1: split(sigmoid(wx[g0+m,n]+acc) * (FH+FL)[m,n]) -> Oh/Ol   (rh)
// EPI 2: C = tanh(wx[g0+m,512+n]+acc)                  (h_cand)
// EPI 3: C = acc + bias[n]                             (wx)
template <int EPI>
__global__ __launch_bounds__(256) void mgemm(const unsigned short* __restrict__ Ah,
                                             const unsigned short* __restrict__ Al,
                                             const unsigned short* __restrict__ Bh,
                                             const unsigned short* __restrict__ Bl,
                                             float* __restrict__ C, int ldc, int M,
                                             const float* __restrict__ wx, int g0,
                                             const float* __restrict__ bias,
                                             const unsigned short* __restrict__ FH,
                                             const unsigned short* __restrict__ FL,
                                             unsigned short* __restrict__ Oh,
                                             unsigned short* __restrict__ Ol) {
  __shared__ unsigned short As_h[128][36];
  __shared__ unsigned short As_l[128][36];
  __shared__ unsigned short Bs_h[128][36];
  __shared__ unsigned short Bs_l[128][36];
  const int t = threadIdx.x;
  const int lane = t & 63, wave = t >> 6;
  const int wm = wave & 1, wn = wave >> 1;
  const int m0 = blockIdx.x * 128, n0 = blockIdx.y * 128;

  f32x4 acc[4][4];
#pragma unroll
  for (int i = 0; i < 4; ++i)
#pragma unroll
    for (int j = 0; j < 4; ++j) acc[i][j] = (f32x4){0.f, 0.f, 0.f, 0.f};

  const int r0 = t >> 2, r1 = r0 + 64;  // rows staged by this thread
  const int q0 = (t & 3) * 8;           // k-offset (elements)
  const int fr = lane & 15, fq = (lane >> 4) * 8;

  for (int k0 = 0; k0 < 512; k0 += 32) {
#pragma unroll
    for (int hh = 0; hh < 2; ++hh) {
      const int r = hh ? r1 : r0;
      const int gr = m0 + r;
      uint4 a4 = {0u, 0u, 0u, 0u}, c4 = {0u, 0u, 0u, 0u};
      if (gr < M) {
        a4 = *(const uint4*)(Ah + (size_t)gr * 512 + k0 + q0);
        c4 = *(const uint4*)(Al + (size_t)gr * 512 + k0 + q0);
      }
      *(uint2*)&As_h[r][q0] = make_uint2(a4.x, a4.y);
      *(uint2*)&As_h[r][q0 + 4] = make_uint2(a4.z, a4.w);
      *(uint2*)&As_l[r][q0] = make_uint2(c4.x, c4.y);
      *(uint2*)&As_l[r][q0 + 4] = make_uint2(c4.z, c4.w);
      const uint4 b4 = *(const uint4*)(Bh + (size_t)(n0 + r) * 512 + k0 + q0);
      const uint4 l4 = *(const uint4*)(Bl + (size_t)(n0 + r) * 512 + k0 + q0);
      *(uint2*)&Bs_h[r][q0] = make_uint2(b4.x, b4.y);
      *(uint2*)&Bs_h[r][q0 + 4] = make_uint2(b4.z, b4.w);
      *(uint2*)&Bs_l[r][q0] = make_uint2(l4.x, l4.y);
      *(uint2*)&Bs_l[r][q0 + 4] = make_uint2(l4.z, l4.w);
    }
    __syncthreads();

    bf16x8 ah[4], al[4], bh[4], bl[4];
#pragma unroll
    for (int mt = 0; mt < 4; ++mt) {
      const int row = wm * 64 + mt * 16 + fr;
      FU fa, fb;
      fa.u[0] = *(const ushort4*)&As_h[row][fq];
      fa.u[1] = *(const ushort4*)&As_h[row][fq + 4];
      ah[mt] = fa.v;
      fb.u[0] = *(const ushort4*)&As_l[row][fq];
      fb.u[1] = *(const ushort4*)&As_l[row][fq + 4];
      al[mt] = fb.v;
    }
#pragma unroll
    for (int nt = 0; nt < 4; ++nt) {
      const int row = wn * 64 + nt * 16 + fr;
      FU fa, fb;
      fa.u[0] = *(const ushort4*)&Bs_h[row][fq];
      fa.u[1] = *(const ushort4*)&Bs_h[row][fq + 4];
      bh[nt] = fa.v;
      fb.u[0] = *(const ushort4*)&Bs_l[row][fq];
      fb.u[1] = *(const ushort4*)&Bs_l[row][fq + 4];
      bl[nt] = fb.v;
    }
#pragma unroll
    for (int mt = 0; mt < 4; ++mt)
#pragma unroll
      for (int nt = 0; nt < 4; ++nt) {
        acc[mt][nt] = __builtin_amdgcn_mfma_f32_16x16x32_bf16(ah[mt], bh[nt], acc[mt][nt], 0, 0, 0);
        acc[mt][nt] = __builtin_amdgcn_mfma_f32_16x16x32_bf16(ah[mt], bl[nt], acc[mt][nt], 0, 0, 0);
        acc[mt][nt] = __builtin_amdgcn_mfma_f32_16x16x32_bf16(al[mt], bh[nt], acc[mt][nt], 0, 0, 0);
      }
    __syncthreads();
  }

  // C/D layout: col=lane&15, row=(lane>>4)*4+reg
  const int ecol = lane & 15;
  const int erow = (lane >> 4) * 4;
#pragma unroll
  for (int mt = 0; mt < 4; ++mt) {
#pragma unroll
    for (int nt = 0; nt < 4; ++nt) {
      const int col = n0 + wn * 64 + nt * 16 + ecol;
#pragma unroll
      for (int r = 0; r < 4; ++r) {
        const int row = m0 + wm * 64 + mt * 16 + erow + r;
        if (row >= M) continue;
        const float v = acc[mt][nt][r];
        if (EPI == 0) {
          C[(size_t)row * ldc + col] = v;
        } else if (EPI == 1) {
          const size_t ix = (size_t)row * 512 + col;
          const float hs = bf2f(FH[ix]) + bf2f(FL[ix]);
          const float rg = sigmoidf_(wx[(size_t)(g0 + row) * 1536 + col] + v);
          unsigned short oh, ol;
          split2(rg * hs, oh, ol);
          Oh[ix] = oh;
          Ol[ix] = ol;
        } else if (EPI == 2) {
          C[(size_t)row * ldc + col] = tanhf_(wx[(size_t)(g0 + row) * 1536 + 512 + col] + v);
        } else {
          C[(size_t)row * ldc + col] = v + bias[col];
        }
      }
    }
  }
}

// ---------------- fused leaf kernel: h = (1-sig(x@Wz^T+bz)) * tanh(x@Wh^T+bh) ----------------
// tile 128 rows x 64 cols, both gates accumulated; B-LDS rows 0..63 = h-gate, 64..127 = z-gate.
// A = pre-split leaf x. Writes fp32 h to out AND (hi,lo) split to hcH/hcL.
__global__ __launch_bounds__(256) void mleaf(const unsigned short* __restrict__ xh,
                                             const unsigned short* __restrict__ xl,
                                             const unsigned short* __restrict__ Wh,
                                             const unsigned short* __restrict__ Wl,
                                             const float* __restrict__ bw,
                                             float* __restrict__ out,
                                             unsigned short* __restrict__ hcH,
                                             unsigned short* __restrict__ hcL) {
  __shared__ unsigned short As_h[128][36];
  __shared__ unsigned short As_l[128][36];
  __shared__ unsigned short Bs_h[128][36];
  __shared__ unsigned short Bs_l[128][36];
  const int t = threadIdx.x;
  const int lane = t & 63, wave = t >> 6;
  const int wm = wave & 1, wn = wave >> 1;
  const int m0 = blockIdx.x * 128, n0 = blockIdx.y * 64;

  f32x4 acch[4][2], accz[4][2];
#pragma unroll
  for (int i = 0; i < 4; ++i)
#pragma unroll
    for (int j = 0; j < 2; ++j) {
      acch[i][j] = (f32x4){0.f, 0.f, 0.f, 0.f};
      accz[i][j] = (f32x4){0.f, 0.f, 0.f, 0.f};
    }

  const int r0 = t >> 2, r1 = r0 + 64;
  const int q0 = (t & 3) * 8;
  const int fr = lane & 15, fq = (lane >> 4) * 8;

  for (int k0 = 0; k0 < 512; k0 += 32) {
#pragma unroll
    for (int hh = 0; hh < 2; ++hh) {
      const int r = hh ? r1 : r0;
      const uint4 a4 = *(const uint4*)(xh + (size_t)(m0 + r) * 512 + k0 + q0);
      const uint4 c4 = *(const uint4*)(xl + (size_t)(m0 + r) * 512 + k0 + q0);
      *(uint2*)&As_h[r][q0] = make_uint2(a4.x, a4.y);
      *(uint2*)&As_h[r][q0 + 4] = make_uint2(a4.z, a4.w);
      *(uint2*)&As_l[r][q0] = make_uint2(c4.x, c4.y);
      *(uint2*)&As_l[r][q0 + 4] = make_uint2(c4.z, c4.w);
      // B row: r0 -> h-gate row 512+n0+r0 ; r1 -> z-gate row 1024+n0+r0
      const int br = hh ? (1024 + n0 + (r - 64)) : (512 + n0 + r);
      const uint4 b4 = *(const uint4*)(Wh + (size_t)br * 512 + k0 + q0);
      const uint4 l4 = *(const uint4*)(Wl + (size_t)br * 512 + k0 + q0);
      *(uint2*)&Bs_h[r][q0] = make_uint2(b4.x, b4.y);
      *(uint2*)&Bs_h[r][q0 + 4] = make_uint2(b4.z, b4.w);
      *(uint2*)&Bs_l[r][q0] = make_uint2(l4.x, l4.y);
      *(uint2*)&Bs_l[r][q0 + 4] = make_uint2(l4.z, l4.w);
    }
    __syncthreads();

    bf16x8 ah[4], al[4], bhh[2], bhl[2], bzh[2], bzl[2];
#pragma unroll
    for (int mt = 0; mt < 4; ++mt) {
      const int row = wm * 64 + mt * 16 + fr;
      FU fa, fb;
      fa.u[0] = *(const ushort4*)&As_h[row][fq];
      fa.u[1] = *(const ushort4*)&As_h[row][fq + 4];
      ah[mt] = fa.v;
      fb.u[0] = *(const ushort4*)&As_l[row][fq];
      fb.u[1] = *(const ushort4*)&As_l[row][fq + 4];
      al[mt] = fb.v;
    }
#pragma unroll
    for (int nt = 0; nt < 2; ++nt) {
      const int rh_ = wn * 32 + nt * 16 + fr;
      const int rz_ = 64 + wn * 32 + nt * 16 + fr;
      FU a, b, c, d;
      a.u[0] = *(const ushort4*)&Bs_h[rh_][fq];
      a.u[1] = *(const ushort4*)&Bs_h[rh_][fq + 4];
      bhh[nt] = a.v;
      b.u[0] = *(const ushort4*)&Bs_l[rh_][fq];
      b.u[1] = *(const ushort4*)&Bs_l[rh_][fq + 4];
      bhl[nt] = b.v;
      c.u[0] = *(const ushort4*)&Bs_h[rz_][fq];
      c.u[1] = *(const ushort4*)&Bs_h[rz_][fq + 4];
      bzh[nt] = c.v;
      d.u[0] = *(const ushort4*)&Bs_l[rz_][fq];
      d.u[1] = *(const ushort4*)&Bs_l[rz_][fq + 4];
      bzl[nt] = d.v;
    }
#pragma unroll
    for (int mt = 0; mt < 4; ++mt)
#pragma unroll
      for (int nt = 0; nt < 2; ++nt) {
        acch[mt][nt] = __builtin_amdgcn_mfma_f32_16x16x32_bf16(ah[mt], bhh[nt], acch[mt][nt], 0, 0, 0);
        acch[mt][nt] = __builtin_amdgcn_mfma_f32_16x16x32_bf16(ah[mt], bhl[nt], acch[mt][nt], 0, 0, 0);
        acch[mt][nt] = __builtin_amdgcn_mfma_f32_16x16x32_bf16(al[mt], bhh[nt], acch[mt][nt], 0, 0, 0);
        accz[mt][nt] = __builtin_amdgcn_mfma_f32_16x16x32_bf16(ah[mt], bzh[nt], accz[mt][nt], 0, 0, 0);
        accz[mt][nt] = __builtin_amdgcn_mfma_f32_16x16x32_bf16(ah[mt], bzl[nt], accz[mt][nt], 0, 0, 0);
        accz[mt][nt] = __builtin_amdgcn_mfma_f32_16x16x32_bf16(al[mt], bzh[nt], accz[mt][nt], 0, 0, 0);
      }
    __syncthreads();
  }

  const int ecol = lane & 15;
  const int erow = (lane >> 4) * 4;
#pragma unroll
  for (int mt = 0; mt < 4; ++mt) {
#pragma unroll
    for (int nt = 0; nt < 2; ++nt) {
      const int col = n0 + wn * 32 + nt * 16 + ecol;
      const float bh_ = bw[512 + col];
      const float bz_ = bw[1024 + col];
#pragma unroll
      for (int r = 0; r < 4; ++r) {
        const int row = m0 + wm * 64 + mt * 16 + erow + r;
        const float vh = acch[mt][nt][r] + bh_;
        const float vz = accz[mt][nt][r] + bz_;
        const float hval = (1.f - sigmoidf_(vz)) * tanhf_(vh);
        out[(size_t)(NINT + row) * 512 + col] = hval;
        unsigned short oh, ol;
        split2(hval, oh, ol);
        const size_t ix = (size_t)row * 512 + col;
        hcH[ix] = oh;
        hcL[ix] = ol;
      }
    }
  }
}

// ---------------- child sum (writes split directly) ----------------
__global__ __launch_bounds__(256) void child_sum_k(const float* __restrict__ out,
                                                   int cbase, int nl,
                                                   unsigned short* __restrict__ hH,
                                                   unsigned short* __restrict__ hL) {
  const int idx = blockIdx.x * 256 + threadIdx.x;
  if (idx >= nl * 128) return;
  const int i = idx >> 7;
  const int jq = (idx & 127) << 2;
  const float* b = out + (size_t)(cbase + 4 * i) * 512 + jq;
  const float4 a = *(const float4*)(b);
  const float4 c = *(const float4*)(b + 512);
  const float4 d = *(const float4*)(b + 1024);
  const float4 e = *(const float4*)(b + 1536);
  float4 s;
  s.x = a.x + c.x + d.x + e.x;
  s.y = a.y + c.y + d.y + e.y;
  s.z = a.z + c.z + d.z + e.z;
  s.w = a.w + c.w + d.w + e.w;
  ushort4 sh, sl;
  split2(s.x, sh.x, sl.x); split2(s.y, sh.y, sl.y);
  split2(s.z, sh.z, sl.z); split2(s.w, sh.w, sl.w);
  *(ushort4*)(hH + (size_t)i * 512 + jq) = sh;
  *(ushort4*)(hL + (size_t)i * 512 + jq) = sl;
}

// ---------------- combine (also writes split h for next level's z_e) ----------------
__global__ __launch_bounds__(256) void combine_k(float* __restrict__ out,
                                                 const float* __restrict__ ze,
                                                 const float* __restrict__ wx,
                                                 int pbase, int cbase, int nl,
                                                 unsigned short* __restrict__ hcH,
                                                 unsigned short* __restrict__ hcL) {
  const int idx = blockIdx.x * 256 + threadIdx.x;
  if (idx >= nl * 128) return;
  const int i = idx >> 7;
  const int jq = (idx & 127) << 2;
  const float4 wz = *(const float4*)(wx + (size_t)(pbase + i) * 1536 + 1024 + jq);
  float4 hpre = make_float4(0.f, 0.f, 0.f, 0.f);
  float4 zs = make_float4(0.f, 0.f, 0.f, 0.f);
#pragma unroll
  for (int c = 0; c < 4; ++c) {
    const float4 z = *(const float4*)(ze + (size_t)(4 * i + c) * 512 + jq);
    const float4 h = *(const float4*)(out + (size_t)(cbase + 4 * i + c) * 512 + jq);
    hpre.x = fmaf(z.x, h.x, hpre.x);
    hpre.y = fmaf(z.y, h.y, hpre.y);
    hpre.z = fmaf(z.z, h.z, hpre.z);
    hpre.w = fmaf(z.w, h.w, hpre.w);
    zs.x += sigmoidf_(z.x + wz.x);
    zs.y += sigmoidf_(z.y + wz.y);
    zs.z += sigmoidf_(z.z + wz.z);
    zs.w += sigmoidf_(z.w + wz.w);
  }
  float* po = out + (size_t)(pbase + i) * 512 + jq;
  const float4 hc = *(const float4*)po;
  float4 r;
  r.x = hpre.x + (1.f - zs.x) * hc.x;
  r.y = hpre.y + (1.f - zs.y) * hc.y;
  r.z = hpre.z + (1.f - zs.z) * hc.z;
  r.w = hpre.w + (1.f - zs.w) * hc.w;
  *(float4*)po = r;
  ushort4 ch, cl;
  split2(r.x, ch.x, cl.x); split2(r.y, ch.y, cl.y);
  split2(r.z, ch.z, cl.z); split2(r.w, ch.w, cl.w);
  *(ushort4*)(hcH + (size_t)i * 512 + jq) = ch;
  *(ushort4*)(hcL + (size_t)i * 512 + jq) = cl;
}

extern "C" void kernel_launch(void* const* d_in, const int* in_sizes, int n_in,
                              void* d_out, int out_size, void* d_ws, size_t ws_size,
                              hipStream_t stream) {
  const float* x   = (const float*)d_in[0];
  const float* Ww  = (const float*)d_in[1];
  const float* bw  = (const float*)d_in[2];
  const float* Ur  = (const float*)d_in[3];
  const float* Uhc = (const float*)d_in[4];
  const float* Uz  = (const float*)d_in[5];
  float* out = (float*)d_out;

  // workspace (~487 MB):
  //   region R0 (179.0 MB): x_hi|x_lo during GEMM phase; after mleaf the same
  //     region is reused as ze (134.2 MB fp32) and rh split (33.5 MB) —
  //     lifetimes are disjoint (x dead after mleaf; rh dead before ze write).
  //   wx_int 134.2 | hsum split 33.6 | hc split 134.2 | weight splits 6.3
  char* p = (char*)d_ws;
  unsigned short* x_hi = (unsigned short*)p;
  unsigned short* x_lo = x_hi + (size_t)NNODES * 512;
  float* ze = (float*)p;                     // alias R0 (live after mleaf)
  unsigned short* rhH = (unsigned short*)p;  // alias R0 (rh dead before ze write)
  unsigned short* rhL = rhH + (size_t)16384 * 512;
  p += (size_t)NNODES * 512 * 4;
  float* wx_int = (float*)p;                 p += (size_t)NINT * 1536 * 4;
  unsigned short* hsH = (unsigned short*)p;  p += (size_t)16384 * 512 * 2;
  unsigned short* hsL = (unsigned short*)p;  p += (size_t)16384 * 512 * 2;
  unsigned short* hcH = (unsigned short*)p;  p += (size_t)65536 * 512 * 2;
  unsigned short* hcL = (unsigned short*)p;  p += (size_t)65536 * 512 * 2;
  unsigned short* W_hi = (unsigned short*)p;   p += (size_t)1536 * 512 * 2;
  unsigned short* W_lo = (unsigned short*)p;   p += (size_t)1536 * 512 * 2;
  unsigned short* Ur_hi = (unsigned short*)p;  p += (size_t)512 * 512 * 2;
  unsigned short* Ur_lo = (unsigned short*)p;  p += (size_t)512 * 512 * 2;
  unsigned short* Uhc_hi = (unsigned short*)p; p += (size_t)512 * 512 * 2;
  unsigned short* Uhc_lo = (unsigned short*)p; p += (size_t)512 * 512 * 2;
  unsigned short* Uz_hi = (unsigned short*)p;  p += (size_t)512 * 512 * 2;
  unsigned short* Uz_lo = (unsigned short*)p;  p += (size_t)512 * 512 * 2;

  // 1. split weights + x
  split_k<<<(1536 * 512 / 4 + 255) / 256, 256, 0, stream>>>(Ww, W_hi, W_lo, 1536 * 512 / 4);
  split_k<<<(512 * 512 / 4 + 255) / 256, 256, 0, stream>>>(Ur, Ur_hi, Ur_lo, 512 * 512 / 4);
  split_k<<<(512 * 512 / 4 + 255) / 256, 256, 0, stream>>>(Uhc, Uhc_hi, Uhc_lo, 512 * 512 / 4);
  split_k<<<(512 * 512 / 4 + 255) / 256, 256, 0, stream>>>(Uz, Uz_hi, Uz_lo, 512 * 512 / 4);
  split_k<<<((int)((size_t)NNODES * 512 / 4) + 255) / 256, 256, 0, stream>>>(
      x, x_hi, x_lo, (int)((size_t)NNODES * 512 / 4));

  // 2. wx for internal nodes (3 gates + bias)
  mgemm<3><<<dim3((NINT + 127) / 128, 12), 256, 0, stream>>>(
      x_hi, x_lo, W_hi, W_lo, wx_int, 1536, NINT, nullptr, 0, bw,
      nullptr, nullptr, nullptr, nullptr);

  // 3. fused leaf h -> out (fp32) + hc split
  mleaf<<<dim3(NLEAF / 128, 8), 256, 0, stream>>>(
      x_hi + (size_t)NINT * 512, x_lo + (size_t)NINT * 512, W_hi, W_lo, bw, out, hcH, hcL);

  static const int S[10] = {0, 1, 5, 21, 85, 341, 1365, 5461, 21845, 87381};
  for (int l = 1; l <= 8; ++l) {
    const int d = 8 - l;
    const int pbase = S[d];
    const int nl = S[d + 1] - S[d];
    const int cbase = S[d + 1];
    const int el = 4 * nl;

    child_sum_k<<<(nl * 128 + 255) / 256, 256, 0, stream>>>(out, cbase, nl, hsH, hsL);

    dim3 gr((nl + 127) / 128, 4);
    // rh = sigmoid(wrx + hsum@Ur^T) * hsum  -> split (rhH, rhL)
    mgemm<1><<<gr, 256, 0, stream>>>(hsH, hsL, Ur_hi, Ur_lo, nullptr, 512, nl,
                                     wx_int, pbase, nullptr, hsH, hsL, rhH, rhL);
    // h_cand = tanh(whx + rh@Uhc^T) -> out[parent rows]
    mgemm<2><<<gr, 256, 0, stream>>>(rhH, rhL, Uhc_hi, Uhc_lo,
                                     out + (size_t)pbase * 512, 512, nl,
                                     wx_int, pbase, nullptr, nullptr, nullptr,
                                     nullptr, nullptr);
    // z_e = h_children @ Uz^T (overwrites rh region; rh is dead)
    dim3 gz((el + 127) / 128, 4);
    mgemm<0><<<gz, 256, 0, stream>>>(hcH, hcL, Uz_hi, Uz_lo, ze, 512, el,
                                     nullptr, 0, nullptr, nullptr, nullptr,
                                     nullptr, nullptr);

    combine_k<<<(nl * 128 + 255) / 256, 256, 0, stream>>>(out, ze, wx_int, pbase,
                                                          cbase, nl, hcH, hcL);
  }
}

// Round 2
// 1814.939 us; speedup vs baseline: 1.0781x; 1.0781x over previous
//
#include <hip/hip_runtime.h>

// ChildSumTreeGRU: BRANCH=4, DEPTH=8, N=87381, X=H=512.
// depth-d nodes contiguous at S[d]=(4^d-1)/3; children of p = 4p+1..4p+4.
// R3: pre-split ALL GEMM A-operands to (hi,lo) bf16 at definition site.
// R4: (a) global_load_lds direct staging, linear LDS [128][32] + granule
//         XOR-swizzle (pre-swizzled global source, swizzled ds_read_b128);
//     (b) combine fused into z_e GEMM epilogue (EPI 4) -> ze buffer and
//         combine_k deleted; child-h split buffers ping-pong per level.

#define NNODES 87381
#define NINT   21845
#define NLEAF  65536

typedef __attribute__((ext_vector_type(8))) __bf16 bf16x8;
typedef __attribute__((ext_vector_type(4))) float f32x4;

__device__ __forceinline__ float sigmoidf_(float x) { return 1.0f / (1.0f + __expf(-x)); }
__device__ __forceinline__ float tanhf_(float x) { return 2.0f / (1.0f + __expf(-2.0f * x)) - 1.0f; }

__device__ __forceinline__ unsigned short bf_rne(float f) {
  unsigned int u = __float_as_uint(f);
  unsigned int r = u + 0x7FFFu + ((u >> 16) & 1u);
  return (unsigned short)(r >> 16);
}
__device__ __forceinline__ void split2(float f, unsigned short& h, unsigned short& l) {
  h = bf_rne(f);
  l = bf_rne(f - __uint_as_float((unsigned int)h << 16));
}
__device__ __forceinline__ float bf2f(unsigned short h) {
  return __uint_as_float((unsigned int)h << 16);
}

// ---------------- split fp32 -> (hi, lo) bf16 ----------------
__global__ __launch_bounds__(256) void split_k(const float* __restrict__ s,
                                               unsigned short* __restrict__ hi,
                                               unsigned short* __restrict__ lo, int n4) {
  int i = blockIdx.x * 256 + threadIdx.x;
  if (i >= n4) return;
  float4 v = *(const float4*)(s + (size_t)i * 4);
  ushort4 h, l;
  split2(v.x, h.x, l.x); split2(v.y, h.y, l.y);
  split2(v.z, h.z, l.z); split2(v.w, h.w, l.w);
  *(ushort4*)(hi + (size_t)i * 4) = h;
  *(ushort4*)(lo + (size_t)i * 4) = l;
}

// ---------------- staging: one 128x32 bf16 tile (8 KB) via global_load_lds ----
// LDS linear [128][32] (64 B/row). Swizzle: physical 16B-granule p at LDS row lr
// holds global granule p ^ ((lr>>1)&3). Involution: reads XOR the same value.
// Wave-uniform LDS base (l0 + c*512), per-lane global source (allowed).
template <bool CLAMP>
__device__ __forceinline__ void stage_tile(const unsigned short* __restrict__ g,
                                           int rows_left, unsigned short* l0,
                                           int lane) {
#pragma unroll
  for (int c = 0; c < 8; ++c) {
    const int lr = c * 16 + (lane >> 2);
    const int gr = CLAMP ? (lr < rows_left ? lr : rows_left - 1) : lr;
    const int sg = (lane & 3) ^ ((lr >> 1) & 3);
    __builtin_amdgcn_global_load_lds(
        (const __attribute__((address_space(1))) void*)(g + (size_t)gr * 512 + sg * 8),
        (__attribute__((address_space(3))) void*)(l0 + c * 512), 16, 0, 0);
  }
}

// ---------------- MFMA split-bf16 GEMM ----------------
// C[m,n] = epi( sum_k A[m,k]*B[n,k] ), K=512. tile 128x128, BK=32, 4 waves,
// wave = 64x64 = 4x4 tiles of 16x16x32. 3 MFMAs per tile pair (hh, hl, lh).
// EPI 1: split(sigmoid(wx[g0+m,n]+acc) * (FH+FL)[m,n]) -> Oh/Ol      (rh)
// EPI 2: C = tanh(wx[g0+m,512+n]+acc)                                (h_cand)
// EPI 3: C = acc + bias[n]                                           (wx)
// EPI 4: fused z_e+combine: acc = ze[child=m][n]; each lane's 4 acc rows are
//        one parent's 4 children. bias = children h (out+cbase*512),
//        C = out+pbase*512 (h_cand in / h out), Oh/Ol = next-level child split.
template <int EPI>
__global__ __launch_bounds__(256) void mgemm(const unsigned short* __restrict__ Ah,
                                             const unsigned short* __restrict__ Al,
                                             const unsigned short* __restrict__ Bh,
                                             const unsigned short* __restrict__ Bl,
                                             float* __restrict__ C, int ldc, int M,
                                             const float* __restrict__ wx, int g0,
                                             const float* __restrict__ bias,
                                             const unsigned short* __restrict__ FH,
                                             const unsigned short* __restrict__ FL,
                                             unsigned short* __restrict__ Oh,
                                             unsigned short* __restrict__ Ol) {
  __shared__ unsigned short As_h[128][32];
  __shared__ unsigned short As_l[128][32];
  __shared__ unsigned short Bs_h[128][32];
  __shared__ unsigned short Bs_l[128][32];
  const int t = threadIdx.x;
  const int lane = t & 63, wave = t >> 6;
  const int wm = wave & 1, wn = wave >> 1;
  const int m0 = blockIdx.x * 128, n0 = blockIdx.y * 128;

  f32x4 acc[4][4];
#pragma unroll
  for (int i = 0; i < 4; ++i)
#pragma unroll
    for (int j = 0; j < 4; ++j) acc[i][j] = (f32x4){0.f, 0.f, 0.f, 0.f};

  const int fr = lane & 15, fg = lane >> 4;

  for (int k0 = 0; k0 < 512; k0 += 32) {
    if (wave == 0)      stage_tile<true >(Ah + (size_t)m0 * 512 + k0, M - m0, &As_h[0][0], lane);
    else if (wave == 1) stage_tile<true >(Al + (size_t)m0 * 512 + k0, M - m0, &As_l[0][0], lane);
    else if (wave == 2) stage_tile<false>(Bh + (size_t)n0 * 512 + k0, 0, &Bs_h[0][0], lane);
    else                stage_tile<false>(Bl + (size_t)n0 * 512 + k0, 0, &Bs_l[0][0], lane);
    __syncthreads();  // compiler drains vmcnt before s_barrier

    bf16x8 ah[4], al[4], bh[4], bl[4];
#pragma unroll
    for (int mt = 0; mt < 4; ++mt) {
      const int row = wm * 64 + mt * 16 + fr;
      const int gp = (fg ^ ((row >> 1) & 3)) * 8;
      ah[mt] = *(const bf16x8*)&As_h[row][gp];
      al[mt] = *(const bf16x8*)&As_l[row][gp];
    }
#pragma unroll
    for (int nt = 0; nt < 4; ++nt) {
      const int row = wn * 64 + nt * 16 + fr;
      const int gp = (fg ^ ((row >> 1) & 3)) * 8;
      bh[nt] = *(const bf16x8*)&Bs_h[row][gp];
      bl[nt] = *(const bf16x8*)&Bs_l[row][gp];
    }
#pragma unroll
    for (int mt = 0; mt < 4; ++mt)
#pragma unroll
      for (int nt = 0; nt < 4; ++nt) {
        acc[mt][nt] = __builtin_amdgcn_mfma_f32_16x16x32_bf16(ah[mt], bh[nt], acc[mt][nt], 0, 0, 0);
        acc[mt][nt] = __builtin_amdgcn_mfma_f32_16x16x32_bf16(ah[mt], bl[nt], acc[mt][nt], 0, 0, 0);
        acc[mt][nt] = __builtin_amdgcn_mfma_f32_16x16x32_bf16(al[mt], bh[nt], acc[mt][nt], 0, 0, 0);
      }
    __syncthreads();
  }

  // C/D layout: col=lane&15, row=(lane>>4)*4+reg
  const int ecol = lane & 15;
  const int erow = (lane >> 4) * 4;

  if (EPI == 4) {
#pragma unroll
    for (int mt = 0; mt < 4; ++mt) {
#pragma unroll
      for (int nt = 0; nt < 4; ++nt) {
        const int col = n0 + wn * 64 + nt * 16 + ecol;
        const int row0 = m0 + wm * 64 + mt * 16 + erow;  // multiple of 4
        if (row0 >= M) continue;
        const int p = row0 >> 2;  // local parent index
        const float wz = wx[(size_t)(g0 + p) * 1536 + 1024 + col];
        float hpre = 0.f, zs = 0.f;
#pragma unroll
        for (int r = 0; r < 4; ++r) {
          const float zev = acc[mt][nt][r];
          const float hch = bias[(size_t)(row0 + r) * 512 + col];  // child h (fp32)
          hpre = fmaf(zev, hch, hpre);
          zs += sigmoidf_(zev + wz);
        }
        float* po = C + (size_t)p * 512 + col;
        const float hc = *po;  // h_cand from mgemm<2>
        const float res = hpre + (1.f - zs) * hc;
        *po = res;
        unsigned short oh, ol;
        split2(res, oh, ol);
        Oh[(size_t)p * 512 + col] = oh;
        Ol[(size_t)p * 512 + col] = ol;
      }
    }
    return;
  }

#pragma unroll
  for (int mt = 0; mt < 4; ++mt) {
#pragma unroll
    for (int nt = 0; nt < 4; ++nt) {
      const int col = n0 + wn * 64 + nt * 16 + ecol;
#pragma unroll
      for (int r = 0; r < 4; ++r) {
        const int row = m0 + wm * 64 + mt * 16 + erow + r;
        if (row >= M) continue;
        const float v = acc[mt][nt][r];
        if (EPI == 1) {
          const size_t ix = (size_t)row * 512 + col;
          const float hs = bf2f(FH[ix]) + bf2f(FL[ix]);
          const float rg = sigmoidf_(wx[(size_t)(g0 + row) * 1536 + col] + v);
          unsigned short oh, ol;
          split2(rg * hs, oh, ol);
          Oh[ix] = oh;
          Ol[ix] = ol;
        } else if (EPI == 2) {
          C[(size_t)row * ldc + col] = tanhf_(wx[(size_t)(g0 + row) * 1536 + 512 + col] + v);
        } else {
          C[(size_t)row * ldc + col] = v + bias[col];
        }
      }
    }
  }
}

// ---------------- fused leaf kernel: h = (1-sig(x@Wz^T+bz)) * tanh(x@Wh^T+bh) ----------------
// tile 128 rows x 64 cols; B-LDS rows 0..63 = h-gate (W rows 512+n0+r),
// rows 64..127 = z-gate (W rows 1024+n0+r). Writes fp32 h to out AND split to hcH/hcL.
__global__ __launch_bounds__(256) void mleaf(const unsigned short* __restrict__ xh,
                                             const unsigned short* __restrict__ xl,
                                             const unsigned short* __restrict__ Wh,
                                             const unsigned short* __restrict__ Wl,
                                             const float* __restrict__ bw,
                                             float* __restrict__ out,
                                             unsigned short* __restrict__ hcH,
                                             unsigned short* __restrict__ hcL) {
  __shared__ unsigned short As_h[128][32];
  __shared__ unsigned short As_l[128][32];
  __shared__ unsigned short Bs_h[128][32];
  __shared__ unsigned short Bs_l[128][32];
  const int t = threadIdx.x;
  const int lane = t & 63, wave = t >> 6;
  const int wm = wave & 1, wn = wave >> 1;
  const int m0 = blockIdx.x * 128, n0 = blockIdx.y * 64;

  f32x4 acch[4][2], accz[4][2];
#pragma unroll
  for (int i = 0; i < 4; ++i)
#pragma unroll
    for (int j = 0; j < 2; ++j) {
      acch[i][j] = (f32x4){0.f, 0.f, 0.f, 0.f};
      accz[i][j] = (f32x4){0.f, 0.f, 0.f, 0.f};
    }

  const int fr = lane & 15, fg = lane >> 4;

  for (int k0 = 0; k0 < 512; k0 += 32) {
    if (wave == 0) {
      stage_tile<false>(xh + (size_t)m0 * 512 + k0, 0, &As_h[0][0], lane);
    } else if (wave == 1) {
      stage_tile<false>(xl + (size_t)m0 * 512 + k0, 0, &As_l[0][0], lane);
    } else {
      const unsigned short* Ws = (wave == 2) ? Wh : Wl;
      unsigned short* dst = (wave == 2) ? &Bs_h[0][0] : &Bs_l[0][0];
#pragma unroll
      for (int c = 0; c < 8; ++c) {
        const int lr = c * 16 + (lane >> 2);
        const int grow = (lr < 64) ? (512 + n0 + lr) : (1024 + n0 + (lr - 64));
        const int sg = (lane & 3) ^ ((lr >> 1) & 3);
        __builtin_amdgcn_global_load_lds(
            (const __attribute__((address_space(1))) void*)(Ws + (size_t)grow * 512 + k0 + sg * 8),
            (__attribute__((address_space(3))) void*)(dst + c * 512), 16, 0, 0);
      }
    }
    __syncthreads();

    bf16x8 ah[4], al[4], bhh[2], bhl[2], bzh[2], bzl[2];
#pragma unroll
    for (int mt = 0; mt < 4; ++mt) {
      const int row = wm * 64 + mt * 16 + fr;
      const int gp = (fg ^ ((row >> 1) & 3)) * 8;
      ah[mt] = *(const bf16x8*)&As_h[row][gp];
      al[mt] = *(const bf16x8*)&As_l[row][gp];
    }
#pragma unroll
    for (int nt = 0; nt < 2; ++nt) {
      const int rh_ = wn * 32 + nt * 16 + fr;
      const int rz_ = 64 + rh_;
      const int gph = (fg ^ ((rh_ >> 1) & 3)) * 8;
      const int gpz = (fg ^ ((rz_ >> 1) & 3)) * 8;
      bhh[nt] = *(const bf16x8*)&Bs_h[rh_][gph];
      bhl[nt] = *(const bf16x8*)&Bs_l[rh_][gph];
      bzh[nt] = *(const bf16x8*)&Bs_h[rz_][gpz];
      bzl[nt] = *(const bf16x8*)&Bs_l[rz_][gpz];
    }
#pragma unroll
    for (int mt = 0; mt < 4; ++mt)
#pragma unroll
      for (int nt = 0; nt < 2; ++nt) {
        acch[mt][nt] = __builtin_amdgcn_mfma_f32_16x16x32_bf16(ah[mt], bhh[nt], acch[mt][nt], 0, 0, 0);
        acch[mt][nt] = __builtin_amdgcn_mfma_f32_16x16x32_bf16(ah[mt], bhl[nt], acch[mt][nt], 0, 0, 0);
        acch[mt][nt] = __builtin_amdgcn_mfma_f32_16x16x32_bf16(al[mt], bhh[nt], acch[mt][nt], 0, 0, 0);
        accz[mt][nt] = __builtin_amdgcn_mfma_f32_16x16x32_bf16(ah[mt], bzh[nt], accz[mt][nt], 0, 0, 0);
        accz[mt][nt] = __builtin_amdgcn_mfma_f32_16x16x32_bf16(ah[mt], bzl[nt], accz[mt][nt], 0, 0, 0);
        accz[mt][nt] = __builtin_amdgcn_mfma_f32_16x16x32_bf16(al[mt], bzh[nt], accz[mt][nt], 0, 0, 0);
      }
    __syncthreads();
  }

  const int ecol = lane & 15;
  const int erow = (lane >> 4) * 4;
#pragma unroll
  for (int mt = 0; mt < 4; ++mt) {
#pragma unroll
    for (int nt = 0; nt < 2; ++nt) {
      const int col = n0 + wn * 32 + nt * 16 + ecol;
      const float bh_ = bw[512 + col];
      const float bz_ = bw[1024 + col];
#pragma unroll
      for (int r = 0; r < 4; ++r) {
        const int row = m0 + wm * 64 + mt * 16 + erow + r;
        const float vh = acch[mt][nt][r] + bh_;
        const float vz = accz[mt][nt][r] + bz_;
        const float hval = (1.f - sigmoidf_(vz)) * tanhf_(vh);
        out[(size_t)(NINT + row) * 512 + col] = hval;
        unsigned short oh, ol;
        split2(hval, oh, ol);
        const size_t ix = (size_t)row * 512 + col;
        hcH[ix] = oh;
        hcL[ix] = ol;
      }
    }
  }
}

// ---------------- child sum (writes split directly) ----------------
__global__ __launch_bounds__(256) void child_sum_k(const float* __restrict__ out,
                                                   int cbase, int nl,
                                                   unsigned short* __restrict__ hH,
                                                   unsigned short* __restrict__ hL) {
  const int idx = blockIdx.x * 256 + threadIdx.x;
  if (idx >= nl * 128) return;
  const int i = idx >> 7;
  const int jq = (idx & 127) << 2;
  const float* b = out + (size_t)(cbase + 4 * i) * 512 + jq;
  const float4 a = *(const float4*)(b);
  const float4 c = *(const float4*)(b + 512);
  const float4 d = *(const float4*)(b + 1024);
  const float4 e = *(const float4*)(b + 1536);
  float4 s;
  s.x = a.x + c.x + d.x + e.x;
  s.y = a.y + c.y + d.y + e.y;
  s.z = a.z + c.z + d.z + e.z;
  s.w = a.w + c.w + d.w + e.w;
  ushort4 sh, sl;
  split2(s.x, sh.x, sl.x); split2(s.y, sh.y, sl.y);
  split2(s.z, sh.z, sl.z); split2(s.w, sh.w, sl.w);
  *(ushort4*)(hH + (size_t)i * 512 + jq) = sh;
  *(ushort4*)(hL + (size_t)i * 512 + jq) = sl;
}

extern "C" void kernel_launch(void* const* d_in, const int* in_sizes, int n_in,
                              void* d_out, int out_size, void* d_ws, size_t ws_size,
                              hipStream_t stream) {
  const float* x   = (const float*)d_in[0];
  const float* Ww  = (const float*)d_in[1];
  const float* bw  = (const float*)d_in[2];
  const float* Ur  = (const float*)d_in[3];
  const float* Uhc = (const float*)d_in[4];
  const float* Uz  = (const float*)d_in[5];
  float* out = (float*)d_out;

  // workspace (~521 MB):
  //   R0 (179 MB): x split during GEMM phase; rh split aliases after x dies.
  //   wx_int 134.2 | hsum split 33.6 | hc split A 134.2 | hc split B 33.6 | W splits 6.3
  char* p = (char*)d_ws;
  unsigned short* x_hi = (unsigned short*)p;
  unsigned short* x_lo = x_hi + (size_t)NNODES * 512;
  unsigned short* rhH = (unsigned short*)p;  // alias R0 (x dead in level loop)
  unsigned short* rhL = rhH + (size_t)16384 * 512;
  p += (size_t)NNODES * 512 * 4;
  float* wx_int = (float*)p;                 p += (size_t)NINT * 1536 * 4;
  unsigned short* hsH = (unsigned short*)p;  p += (size_t)16384 * 512 * 2;
  unsigned short* hsL = (unsigned short*)p;  p += (size_t)16384 * 512 * 2;
  unsigned short* hcH = (unsigned short*)p;  p += (size_t)65536 * 512 * 2;
  unsigned short* hcL = (unsigned short*)p;  p += (size_t)65536 * 512 * 2;
  unsigned short* hc2H = (unsigned short*)p; p += (size_t)16384 * 512 * 2;
  unsigned short* hc2L = (unsigned short*)p; p += (size_t)16384 * 512 * 2;
  unsigned short* W_hi = (unsigned short*)p;   p += (size_t)1536 * 512 * 2;
  unsigned short* W_lo = (unsigned short*)p;   p += (size_t)1536 * 512 * 2;
  unsigned short* Ur_hi = (unsigned short*)p;  p += (size_t)512 * 512 * 2;
  unsigned short* Ur_lo = (unsigned short*)p;  p += (size_t)512 * 512 * 2;
  unsigned short* Uhc_hi = (unsigned short*)p; p += (size_t)512 * 512 * 2;
  unsigned short* Uhc_lo = (unsigned short*)p; p += (size_t)512 * 512 * 2;
  unsigned short* Uz_hi = (unsigned short*)p;  p += (size_t)512 * 512 * 2;
  unsigned short* Uz_lo = (unsigned short*)p;  p += (size_t)512 * 512 * 2;

  // 1. split weights + x
  split_k<<<(1536 * 512 / 4 + 255) / 256, 256, 0, stream>>>(Ww, W_hi, W_lo, 1536 * 512 / 4);
  split_k<<<(512 * 512 / 4 + 255) / 256, 256, 0, stream>>>(Ur, Ur_hi, Ur_lo, 512 * 512 / 4);
  split_k<<<(512 * 512 / 4 + 255) / 256, 256, 0, stream>>>(Uhc, Uhc_hi, Uhc_lo, 512 * 512 / 4);
  split_k<<<(512 * 512 / 4 + 255) / 256, 256, 0, stream>>>(Uz, Uz_hi, Uz_lo, 512 * 512 / 4);
  split_k<<<((int)((size_t)NNODES * 512 / 4) + 255) / 256, 256, 0, stream>>>(
      x, x_hi, x_lo, (int)((size_t)NNODES * 512 / 4));

  // 2. wx for internal nodes (3 gates + bias)
  mgemm<3><<<dim3((NINT + 127) / 128, 12), 256, 0, stream>>>(
      x_hi, x_lo, W_hi, W_lo, wx_int, 1536, NINT, nullptr, 0, bw,
      nullptr, nullptr, nullptr, nullptr);

  // 3. fused leaf h -> out (fp32) + hc split
  mleaf<<<dim3(NLEAF / 128, 8), 256, 0, stream>>>(
      x_hi + (size_t)NINT * 512, x_lo + (size_t)NINT * 512, W_hi, W_lo, bw, out, hcH, hcL);

  static const int S[10] = {0, 1, 5, 21, 85, 341, 1365, 5461, 21845, 87381};
  unsigned short *rdH = hcH, *rdL = hcL, *wrH = hc2H, *wrL = hc2L;
  for (int l = 1; l <= 8; ++l) {
    const int d = 8 - l;
    const int pbase = S[d];
    const int nl = S[d + 1] - S[d];
    const int cbase = S[d + 1];
    const int el = 4 * nl;

    child_sum_k<<<(nl * 128 + 255) / 256, 256, 0, stream>>>(out, cbase, nl, hsH, hsL);

    dim3 gr((nl + 127) / 128, 4);
    // rh = sigmoid(wrx + hsum@Ur^T) * hsum  -> split (rhH, rhL)
    mgemm<1><<<gr, 256, 0, stream>>>(hsH, hsL, Ur_hi, Ur_lo, nullptr, 512, nl,
                                     wx_int, pbase, nullptr, hsH, hsL, rhH, rhL);
    // h_cand = tanh(whx + rh@Uhc^T) -> out[parent rows]
    mgemm<2><<<gr, 256, 0, stream>>>(rhH, rhL, Uhc_hi, Uhc_lo,
                                     out + (size_t)pbase * 512, 512, nl,
                                     wx_int, pbase, nullptr, nullptr, nullptr,
                                     nullptr, nullptr);
    // fused z_e + combine: reads child split (rd), child h (out+cbase),
    // h_cand (out+pbase); writes h (out+pbase) + next-level child split (wr).
    dim3 gz((el + 127) / 128, 4);
    mgemm<4><<<gz, 256, 0, stream>>>(rdH, rdL, Uz_hi, Uz_lo,
                                     out + (size_t)pbase * 512, 512, el,
                                     wx_int, pbase, out + (size_t)cbase * 512,
                                     nullptr, nullptr, wrH, wrL);
    // ping-pong child-h split buffers (EPI4 writes parents while reading children)
    unsigned short* tH = rdH; rdH = wrH; wrH = tH;
    unsigned short* tL = rdL; rdL = wrL; wrL = tL;
  }
}

// Round 3
// 1758.779 us; speedup vs baseline: 1.1126x; 1.0319x over previous
//
#include <hip/hip_runtime.h>

// ChildSumTreeGRU: BRANCH=4, DEPTH=8, N=87381, X=H=512.
// depth-d nodes contiguous at S[d]=(4^d-1)/3; children of p = 4p+1..4p+4.
// R3: pre-split ALL GEMM A-operands to (hi,lo) bf16 at definition site.
// R4: global_load_lds direct staging + granule XOR swizzle (0 bank conflicts);
//     combine fused into z_e GEMM epilogue (EPI 4).
// R5: T3 minimum 2-phase pipeline: double-buffered LDS [2][128][32], STAGE of
//     tile k+1 issued BEFORE compute of tile k, ONE barrier per K-step.
//     Load latency hides under MFMA; barrier's vmcnt(0) finds loads done.

#define NNODES 87381
#define NINT   21845
#define NLEAF  65536

typedef __attribute__((ext_vector_type(8))) __bf16 bf16x8;
typedef __attribute__((ext_vector_type(4))) float f32x4;

__device__ __forceinline__ float sigmoidf_(float x) { return 1.0f / (1.0f + __expf(-x)); }
__device__ __forceinline__ float tanhf_(float x) { return 2.0f / (1.0f + __expf(-2.0f * x)) - 1.0f; }

__device__ __forceinline__ unsigned short bf_rne(float f) {
  unsigned int u = __float_as_uint(f);
  unsigned int r = u + 0x7FFFu + ((u >> 16) & 1u);
  return (unsigned short)(r >> 16);
}
__device__ __forceinline__ void split2(float f, unsigned short& h, unsigned short& l) {
  h = bf_rne(f);
  l = bf_rne(f - __uint_as_float((unsigned int)h << 16));
}
__device__ __forceinline__ float bf2f(unsigned short h) {
  return __uint_as_float((unsigned int)h << 16);
}

// ---------------- split fp32 -> (hi, lo) bf16 ----------------
__global__ __launch_bounds__(256) void split_k(const float* __restrict__ s,
                                               unsigned short* __restrict__ hi,
                                               unsigned short* __restrict__ lo, int n4) {
  int i = blockIdx.x * 256 + threadIdx.x;
  if (i >= n4) return;
  float4 v = *(const float4*)(s + (size_t)i * 4);
  ushort4 h, l;
  split2(v.x, h.x, l.x); split2(v.y, h.y, l.y);
  split2(v.z, h.z, l.z); split2(v.w, h.w, l.w);
  *(ushort4*)(hi + (size_t)i * 4) = h;
  *(ushort4*)(lo + (size_t)i * 4) = l;
}

// ---------------- staging: one 128x32 bf16 tile (8 KB) via global_load_lds ----
// LDS linear [128][32] (64 B/row). Swizzle: physical 16B-granule p at LDS row lr
// holds global granule p ^ ((lr>>1)&3). Involution: reads XOR the same value.
// Wave-uniform LDS base (l0 + c*512), per-lane global source (allowed).
template <bool CLAMP>
__device__ __forceinline__ void stage_tile(const unsigned short* __restrict__ g,
                                           int rows_left, unsigned short* l0,
                                           int lane) {
#pragma unroll
  for (int c = 0; c < 8; ++c) {
    const int lr = c * 16 + (lane >> 2);
    const int gr = CLAMP ? (lr < rows_left ? lr : rows_left - 1) : lr;
    const int sg = (lane & 3) ^ ((lr >> 1) & 3);
    __builtin_amdgcn_global_load_lds(
        (const __attribute__((address_space(1))) void*)(g + (size_t)gr * 512 + sg * 8),
        (__attribute__((address_space(3))) void*)(l0 + c * 512), 16, 0, 0);
  }
}

// ---------------- MFMA split-bf16 GEMM ----------------
// C[m,n] = epi( sum_k A[m,k]*B[n,k] ), K=512. tile 128x128, BK=32, 4 waves,
// wave = 64x64 = 4x4 tiles of 16x16x32. 3 MFMAs per tile pair (hh, hl, lh).
// EPI 1: split(sigmoid(wx[g0+m,n]+acc) * (FH+FL)[m,n]) -> Oh/Ol      (rh)
// EPI 2: C = tanh(wx[g0+m,512+n]+acc)                                (h_cand)
// EPI 3: C = acc + bias[n]                                           (wx)
// EPI 4: fused z_e+combine: acc = ze[child=m][n]; each lane's 4 acc rows are
//        one parent's 4 children. bias = children h (out+cbase*512),
//        C = out+pbase*512 (h_cand in / h out), Oh/Ol = next-level child split.
template <int EPI>
__global__ __launch_bounds__(256) void mgemm(const unsigned short* __restrict__ Ah,
                                             const unsigned short* __restrict__ Al,
                                             const unsigned short* __restrict__ Bh,
                                             const unsigned short* __restrict__ Bl,
                                             float* __restrict__ C, int ldc, int M,
                                             const float* __restrict__ wx, int g0,
                                             const float* __restrict__ bias,
                                             const unsigned short* __restrict__ FH,
                                             const unsigned short* __restrict__ FL,
                                             unsigned short* __restrict__ Oh,
                                             unsigned short* __restrict__ Ol) {
  __shared__ unsigned short As_h[2][128][32];
  __shared__ unsigned short As_l[2][128][32];
  __shared__ unsigned short Bs_h[2][128][32];
  __shared__ unsigned short Bs_l[2][128][32];
  const int t = threadIdx.x;
  const int lane = t & 63, wave = t >> 6;
  const int wm = wave & 1, wn = wave >> 1;
  const int m0 = blockIdx.x * 128, n0 = blockIdx.y * 128;

  f32x4 acc[4][4];
#pragma unroll
  for (int i = 0; i < 4; ++i)
#pragma unroll
    for (int j = 0; j < 4; ++j) acc[i][j] = (f32x4){0.f, 0.f, 0.f, 0.f};

  const int fr = lane & 15, fg = lane >> 4;

  auto stage = [&](int buf, int k0) {
    if (wave == 0)      stage_tile<true >(Ah + (size_t)m0 * 512 + k0, M - m0, &As_h[buf][0][0], lane);
    else if (wave == 1) stage_tile<true >(Al + (size_t)m0 * 512 + k0, M - m0, &As_l[buf][0][0], lane);
    else if (wave == 2) stage_tile<false>(Bh + (size_t)n0 * 512 + k0, 0, &Bs_h[buf][0][0], lane);
    else                stage_tile<false>(Bl + (size_t)n0 * 512 + k0, 0, &Bs_l[buf][0][0], lane);
  };

  auto comp = [&](int buf) {
    bf16x8 ah[4], al[4], bh[4], bl[4];
#pragma unroll
    for (int mt = 0; mt < 4; ++mt) {
      const int row = wm * 64 + mt * 16 + fr;
      const int gp = (fg ^ ((row >> 1) & 3)) * 8;
      ah[mt] = *(const bf16x8*)&As_h[buf][row][gp];
      al[mt] = *(const bf16x8*)&As_l[buf][row][gp];
    }
#pragma unroll
    for (int nt = 0; nt < 4; ++nt) {
      const int row = wn * 64 + nt * 16 + fr;
      const int gp = (fg ^ ((row >> 1) & 3)) * 8;
      bh[nt] = *(const bf16x8*)&Bs_h[buf][row][gp];
      bl[nt] = *(const bf16x8*)&Bs_l[buf][row][gp];
    }
#pragma unroll
    for (int mt = 0; mt < 4; ++mt)
#pragma unroll
      for (int nt = 0; nt < 4; ++nt) {
        acc[mt][nt] = __builtin_amdgcn_mfma_f32_16x16x32_bf16(ah[mt], bh[nt], acc[mt][nt], 0, 0, 0);
        acc[mt][nt] = __builtin_amdgcn_mfma_f32_16x16x32_bf16(ah[mt], bl[nt], acc[mt][nt], 0, 0, 0);
        acc[mt][nt] = __builtin_amdgcn_mfma_f32_16x16x32_bf16(al[mt], bh[nt], acc[mt][nt], 0, 0, 0);
      }
  };

  // prologue: stage tile 0 into buf 0
  stage(0, 0);
  __syncthreads();
  // 2-phase pipeline: stage(next) issued BEFORE compute(cur); one barrier/step
  for (int kk = 0; kk < 16; kk += 2) {
    stage(1, (kk + 1) * 32);   // prefetch tile kk+1
    comp(0);                   // compute tile kk
    __syncthreads();           // vmcnt(0): prefetch landed; lgkm: reads done
    if (kk < 14) stage(0, (kk + 2) * 32);
    comp(1);                   // compute tile kk+1
    __syncthreads();
  }

  // C/D layout: col=lane&15, row=(lane>>4)*4+reg
  const int ecol = lane & 15;
  const int erow = (lane >> 4) * 4;

  if (EPI == 4) {
#pragma unroll
    for (int mt = 0; mt < 4; ++mt) {
#pragma unroll
      for (int nt = 0; nt < 4; ++nt) {
        const int col = n0 + wn * 64 + nt * 16 + ecol;
        const int row0 = m0 + wm * 64 + mt * 16 + erow;  // multiple of 4
        if (row0 >= M) continue;
        const int p = row0 >> 2;  // local parent index
        const float wz = wx[(size_t)(g0 + p) * 1536 + 1024 + col];
        float hpre = 0.f, zs = 0.f;
#pragma unroll
        for (int r = 0; r < 4; ++r) {
          const float zev = acc[mt][nt][r];
          const float hch = bias[(size_t)(row0 + r) * 512 + col];  // child h (fp32)
          hpre = fmaf(zev, hch, hpre);
          zs += sigmoidf_(zev + wz);
        }
        float* po = C + (size_t)p * 512 + col;
        const float hc = *po;  // h_cand from mgemm<2>
        const float res = hpre + (1.f - zs) * hc;
        *po = res;
        unsigned short oh, ol;
        split2(res, oh, ol);
        Oh[(size_t)p * 512 + col] = oh;
        Ol[(size_t)p * 512 + col] = ol;
      }
    }
    return;
  }

#pragma unroll
  for (int mt = 0; mt < 4; ++mt) {
#pragma unroll
    for (int nt = 0; nt < 4; ++nt) {
      const int col = n0 + wn * 64 + nt * 16 + ecol;
#pragma unroll
      for (int r = 0; r < 4; ++r) {
        const int row = m0 + wm * 64 + mt * 16 + erow + r;
        if (row >= M) continue;
        const float v = acc[mt][nt][r];
        if (EPI == 1) {
          const size_t ix = (size_t)row * 512 + col;
          const float hs = bf2f(FH[ix]) + bf2f(FL[ix]);
          const float rg = sigmoidf_(wx[(size_t)(g0 + row) * 1536 + col] + v);
          unsigned short oh, ol;
          split2(rg * hs, oh, ol);
          Oh[ix] = oh;
          Ol[ix] = ol;
        } else if (EPI == 2) {
          C[(size_t)row * ldc + col] = tanhf_(wx[(size_t)(g0 + row) * 1536 + 512 + col] + v);
        } else {
          C[(size_t)row * ldc + col] = v + bias[col];
        }
      }
    }
  }
}

// ---------------- fused leaf kernel: h = (1-sig(x@Wz^T+bz)) * tanh(x@Wh^T+bh) ----------------
// tile 128 rows x 64 cols; B-LDS rows 0..63 = h-gate (W rows 512+n0+r),
// rows 64..127 = z-gate (W rows 1024+n0+r). Writes fp32 h to out AND split to hcH/hcL.
__global__ __launch_bounds__(256) void mleaf(const unsigned short* __restrict__ xh,
                                             const unsigned short* __restrict__ xl,
                                             const unsigned short* __restrict__ Wh,
                                             const unsigned short* __restrict__ Wl,
                                             const float* __restrict__ bw,
                                             float* __restrict__ out,
                                             unsigned short* __restrict__ hcH,
                                             unsigned short* __restrict__ hcL) {
  __shared__ unsigned short As_h[2][128][32];
  __shared__ unsigned short As_l[2][128][32];
  __shared__ unsigned short Bs_h[2][128][32];
  __shared__ unsigned short Bs_l[2][128][32];
  const int t = threadIdx.x;
  const int lane = t & 63, wave = t >> 6;
  const int wm = wave & 1, wn = wave >> 1;
  const int m0 = blockIdx.x * 128, n0 = blockIdx.y * 64;

  f32x4 acch[4][2], accz[4][2];
#pragma unroll
  for (int i = 0; i < 4; ++i)
#pragma unroll
    for (int j = 0; j < 2; ++j) {
      acch[i][j] = (f32x4){0.f, 0.f, 0.f, 0.f};
      accz[i][j] = (f32x4){0.f, 0.f, 0.f, 0.f};
    }

  const int fr = lane & 15, fg = lane >> 4;

  auto stage = [&](int buf, int k0) {
    if (wave == 0) {
      stage_tile<false>(xh + (size_t)m0 * 512 + k0, 0, &As_h[buf][0][0], lane);
    } else if (wave == 1) {
      stage_tile<false>(xl + (size_t)m0 * 512 + k0, 0, &As_l[buf][0][0], lane);
    } else {
      const unsigned short* Ws = (wave == 2) ? Wh : Wl;
      unsigned short* dst = (wave == 2) ? &Bs_h[buf][0][0] : &Bs_l[buf][0][0];
#pragma unroll
      for (int c = 0; c < 8; ++c) {
        const int lr = c * 16 + (lane >> 2);
        const int grow = (lr < 64) ? (512 + n0 + lr) : (1024 + n0 + (lr - 64));
        const int sg = (lane & 3) ^ ((lr >> 1) & 3);
        __builtin_amdgcn_global_load_lds(
            (const __attribute__((address_space(1))) void*)(Ws + (size_t)grow * 512 + k0 + sg * 8),
            (__attribute__((address_space(3))) void*)(dst + c * 512), 16, 0, 0);
      }
    }
  };

  auto comp = [&](int buf) {
    bf16x8 ah[4], al[4], bhh[2], bhl[2], bzh[2], bzl[2];
#pragma unroll
    for (int mt = 0; mt < 4; ++mt) {
      const int row = wm * 64 + mt * 16 + fr;
      const int gp = (fg ^ ((row >> 1) & 3)) * 8;
      ah[mt] = *(const bf16x8*)&As_h[buf][row][gp];
      al[mt] = *(const bf16x8*)&As_l[buf][row][gp];
    }
#pragma unroll
    for (int nt = 0; nt < 2; ++nt) {
      const int rh_ = wn * 32 + nt * 16 + fr;
      const int rz_ = 64 + rh_;
      const int gph = (fg ^ ((rh_ >> 1) & 3)) * 8;
      const int gpz = (fg ^ ((rz_ >> 1) & 3)) * 8;
      bhh[nt] = *(const bf16x8*)&Bs_h[buf][rh_][gph];
      bhl[nt] = *(const bf16x8*)&Bs_l[buf][rh_][gph];
      bzh[nt] = *(const bf16x8*)&Bs_h[buf][rz_][gpz];
      bzl[nt] = *(const bf16x8*)&Bs_l[buf][rz_][gpz];
    }
#pragma unroll
    for (int mt = 0; mt < 4; ++mt)
#pragma unroll
      for (int nt = 0; nt < 2; ++nt) {
        acch[mt][nt] = __builtin_amdgcn_mfma_f32_16x16x32_bf16(ah[mt], bhh[nt], acch[mt][nt], 0, 0, 0);
        acch[mt][nt] = __builtin_amdgcn_mfma_f32_16x16x32_bf16(ah[mt], bhl[nt], acch[mt][nt], 0, 0, 0);
        acch[mt][nt] = __builtin_amdgcn_mfma_f32_16x16x32_bf16(al[mt], bhh[nt], acch[mt][nt], 0, 0, 0);
        accz[mt][nt] = __builtin_amdgcn_mfma_f32_16x16x32_bf16(ah[mt], bzh[nt], accz[mt][nt], 0, 0, 0);
        accz[mt][nt] = __builtin_amdgcn_mfma_f32_16x16x32_bf16(ah[mt], bzl[nt], accz[mt][nt], 0, 0, 0);
        accz[mt][nt] = __builtin_amdgcn_mfma_f32_16x16x32_bf16(al[mt], bzh[nt], accz[mt][nt], 0, 0, 0);
      }
  };

  stage(0, 0);
  __syncthreads();
  for (int kk = 0; kk < 16; kk += 2) {
    stage(1, (kk + 1) * 32);
    comp(0);
    __syncthreads();
    if (kk < 14) stage(0, (kk + 2) * 32);
    comp(1);
    __syncthreads();
  }

  const int ecol = lane & 15;
  const int erow = (lane >> 4) * 4;
#pragma unroll
  for (int mt = 0; mt < 4; ++mt) {
#pragma unroll
    for (int nt = 0; nt < 2; ++nt) {
      const int col = n0 + wn * 32 + nt * 16 + ecol;
      const float bh_ = bw[512 + col];
      const float bz_ = bw[1024 + col];
#pragma unroll
      for (int r = 0; r < 4; ++r) {
        const int row = m0 + wm * 64 + mt * 16 + erow + r;
        const float vh = acch[mt][nt][r] + bh_;
        const float vz = accz[mt][nt][r] + bz_;
        const float hval = (1.f - sigmoidf_(vz)) * tanhf_(vh);
        out[(size_t)(NINT + row) * 512 + col] = hval;
        unsigned short oh, ol;
        split2(hval, oh, ol);
        const size_t ix = (size_t)row * 512 + col;
        hcH[ix] = oh;
        hcL[ix] = ol;
      }
    }
  }
}

// ---------------- child sum (writes split directly) ----------------
__global__ __launch_bounds__(256) void child_sum_k(const float* __restrict__ out,
                                                   int cbase, int nl,
                                                   unsigned short* __restrict__ hH,
                                                   unsigned short* __restrict__ hL) {
  const int idx = blockIdx.x * 256 + threadIdx.x;
  if (idx >= nl * 128) return;
  const int i = idx >> 7;
  const int jq = (idx & 127) << 2;
  const float* b = out + (size_t)(cbase + 4 * i) * 512 + jq;
  const float4 a = *(const float4*)(b);
  const float4 c = *(const float4*)(b + 512);
  const float4 d = *(const float4*)(b + 1024);
  const float4 e = *(const float4*)(b + 1536);
  float4 s;
  s.x = a.x + c.x + d.x + e.x;
  s.y = a.y + c.y + d.y + e.y;
  s.z = a.z + c.z + d.z + e.z;
  s.w = a.w + c.w + d.w + e.w;
  ushort4 sh, sl;
  split2(s.x, sh.x, sl.x); split2(s.y, sh.y, sl.y);
  split2(s.z, sh.z, sl.z); split2(s.w, sh.w, sl.w);
  *(ushort4*)(hH + (size_t)i * 512 + jq) = sh;
  *(ushort4*)(hL + (size_t)i * 512 + jq) = sl;
}

extern "C" void kernel_launch(void* const* d_in, const int* in_sizes, int n_in,
                              void* d_out, int out_size, void* d_ws, size_t ws_size,
                              hipStream_t stream) {
  const float* x   = (const float*)d_in[0];
  const float* Ww  = (const float*)d_in[1];
  const float* bw  = (const float*)d_in[2];
  const float* Ur  = (const float*)d_in[3];
  const float* Uhc = (const float*)d_in[4];
  const float* Uz  = (const float*)d_in[5];
  float* out = (float*)d_out;

  // workspace (~521 MB):
  //   R0 (179 MB): x split during GEMM phase; rh split aliases after x dies.
  //   wx_int 134.2 | hsum split 33.6 | hc split A 134.2 | hc split B 33.6 | W splits 6.3
  char* p = (char*)d_ws;
  unsigned short* x_hi = (unsigned short*)p;
  unsigned short* x_lo = x_hi + (size_t)NNODES * 512;
  unsigned short* rhH = (unsigned short*)p;  // alias R0 (x dead in level loop)
  unsigned short* rhL = rhH + (size_t)16384 * 512;
  p += (size_t)NNODES * 512 * 4;
  float* wx_int = (float*)p;                 p += (size_t)NINT * 1536 * 4;
  unsigned short* hsH = (unsigned short*)p;  p += (size_t)16384 * 512 * 2;
  unsigned short* hsL = (unsigned short*)p;  p += (size_t)16384 * 512 * 2;
  unsigned short* hcH = (unsigned short*)p;  p += (size_t)65536 * 512 * 2;
  unsigned short* hcL = (unsigned short*)p;  p += (size_t)65536 * 512 * 2;
  unsigned short* hc2H = (unsigned short*)p; p += (size_t)16384 * 512 * 2;
  unsigned short* hc2L = (unsigned short*)p; p += (size_t)16384 * 512 * 2;
  unsigned short* W_hi = (unsigned short*)p;   p += (size_t)1536 * 512 * 2;
  unsigned short* W_lo = (unsigned short*)p;   p += (size_t)1536 * 512 * 2;
  unsigned short* Ur_hi = (unsigned short*)p;  p += (size_t)512 * 512 * 2;
  unsigned short* Ur_lo = (unsigned short*)p;  p += (size_t)512 * 512 * 2;
  unsigned short* Uhc_hi = (unsigned short*)p; p += (size_t)512 * 512 * 2;
  unsigned short* Uhc_lo = (unsigned short*)p; p += (size_t)512 * 512 * 2;
  unsigned short* Uz_hi = (unsigned short*)p;  p += (size_t)512 * 512 * 2;
  unsigned short* Uz_lo = (unsigned short*)p;  p += (size_t)512 * 512 * 2;

  // 1. split weights + x
  split_k<<<(1536 * 512 / 4 + 255) / 256, 256, 0, stream>>>(Ww, W_hi, W_lo, 1536 * 512 / 4);
  split_k<<<(512 * 512 / 4 + 255) / 256, 256, 0, stream>>>(Ur, Ur_hi, Ur_lo, 512 * 512 / 4);
  split_k<<<(512 * 512 / 4 + 255) / 256, 256, 0, stream>>>(Uhc, Uhc_hi, Uhc_lo, 512 * 512 / 4);
  split_k<<<(512 * 512 / 4 + 255) / 256, 256, 0, stream>>>(Uz, Uz_hi, Uz_lo, 512 * 512 / 4);
  split_k<<<((int)((size_t)NNODES * 512 / 4) + 255) / 256, 256, 0, stream>>>(
      x, x_hi, x_lo, (int)((size_t)NNODES * 512 / 4));

  // 2. wx for internal nodes (3 gates + bias)
  mgemm<3><<<dim3((NINT + 127) / 128, 12), 256, 0, stream>>>(
      x_hi, x_lo, W_hi, W_lo, wx_int, 1536, NINT, nullptr, 0, bw,
      nullptr, nullptr, nullptr, nullptr);

  // 3. fused leaf h -> out (fp32) + hc split
  mleaf<<<dim3(NLEAF / 128, 8), 256, 0, stream>>>(
      x_hi + (size_t)NINT * 512, x_lo + (size_t)NINT * 512, W_hi, W_lo, bw, out, hcH, hcL);

  static const int S[10] = {0, 1, 5, 21, 85, 341, 1365, 5461, 21845, 87381};
  unsigned short *rdH = hcH, *rdL = hcL, *wrH = hc2H, *wrL = hc2L;
  for (int l = 1; l <= 8; ++l) {
    const int d = 8 - l;
    const int pbase = S[d];
    const int nl = S[d + 1] - S[d];
    const int cbase = S[d + 1];
    const int el = 4 * nl;

    child_sum_k<<<(nl * 128 + 255) / 256, 256, 0, stream>>>(out, cbase, nl, hsH, hsL);

    dim3 gr((nl + 127) / 128, 4);
    // rh = sigmoid(wrx + hsum@Ur^T) * hsum  -> split (rhH, rhL)
    mgemm<1><<<gr, 256, 0, stream>>>(hsH, hsL, Ur_hi, Ur_lo, nullptr, 512, nl,
                                     wx_int, pbase, nullptr, hsH, hsL, rhH, rhL);
    // h_cand = tanh(whx + rh@Uhc^T) -> out[parent rows]
    mgemm<2><<<gr, 256, 0, stream>>>(rhH, rhL, Uhc_hi, Uhc_lo,
                                     out + (size_t)pbase * 512, 512, nl,
                                     wx_int, pbase, nullptr, nullptr, nullptr,
                                     nullptr, nullptr);
    // fused z_e + combine: reads child split (rd), child h (out+cbase),
    // h_cand (out+pbase); writes h (out+pbase) + next-level child split (wr).
    dim3 gz((el + 127) / 128, 4);
    mgemm<4><<<gz, 256, 0, stream>>>(rdH, rdL, Uz_hi, Uz_lo,
                                     out + (size_t)pbase * 512, 512, el,
                                     wx_int, pbase, out + (size_t)cbase * 512,
                                     nullptr, nullptr, wrH, wrL);
    // ping-pong child-h split buffers (EPI4 writes parents while reading children)
    unsigned short* tH = rdH; rdH = wrH; wrH = tH;
    unsigned short* tL = rdL; rdL = wrL; wrL = tL;
  }
}